// Round 5
// baseline (232.052 us; speedup 1.0000x reference)
//
#include <hip/hip_runtime.h>

#define T_ 4
#define B_ 32
#define C_ 384
#define N_ 256
#define HEADS_ 8
#define DH_ 48
#define EPS_ 1e-5f
#define NW_ (C_*C_)

typedef _Float16 f16;
typedef __attribute__((ext_vector_type(8))) _Float16 f16x8;
typedef __attribute__((ext_vector_type(16))) float f32x16;

#define PSCALE     4096.0f
#define PSCALE_INV (1.0f/4096.0f)

// ---------------------------------------------------------------------------
// Kernel 1: combined input-LIF+transpose (z<32) and weight-split (z==32).
// ---------------------------------------------------------------------------
__global__ __launch_bounds__(256)
void prep_kernel(const float* __restrict__ x, f16* __restrict__ s,
                 const float* __restrict__ qw, const float* __restrict__ kw,
                 const float* __restrict__ pw,
                 f16* __restrict__ q2, f16* __restrict__ k2, f16* __restrict__ p2)
{
    __shared__ f16 Ls[64][72];
    if (blockIdx.z == 32) {
        int idx = (blockIdx.y * 4 + blockIdx.x) * 256 + threadIdx.x;
#pragma unroll
        for (int it = 0; it < 24; ++it) {
            {
                float w = qw[idx]; f16 a = (f16)w; f16 bb = (f16)((w - (float)a) * PSCALE);
                q2[idx] = a; q2[NW_ + idx] = bb;
            }
            {
                float w = kw[idx]; f16 a = (f16)w; f16 bb = (f16)((w - (float)a) * PSCALE);
                k2[idx] = a; k2[NW_ + idx] = bb;
            }
            {
                float w = pw[idx]; f16 a = (f16)w; f16 bb = (f16)((w - (float)a) * PSCALE);
                p2[idx] = a; p2[NW_ + idx] = bb;
            }
            idx += 6144;
        }
        return;
    }

    const int tid = threadIdx.x;
    const int n0 = blockIdx.x * 64;
    const int c0 = blockIdx.y * 64;
    const int b  = blockIdx.z;
    const int cl = tid >> 4;
    const int nl = (tid & 15) * 4;

    float v[4][4];
#pragma unroll
    for (int i = 0; i < 4; ++i)
#pragma unroll
        for (int j = 0; j < 4; ++j) v[i][j] = 0.f;

    for (int t = 0; t < T_; ++t) {
        const float* xt = x + (((size_t)t * B_ + b) * C_) * N_;
#pragma unroll
        for (int i = 0; i < 4; ++i) {
            int c = c0 + cl + 16 * i;
            float4 xv = *(const float4*)&xt[(size_t)c * N_ + n0 + nl];
            float xa[4] = {xv.x, xv.y, xv.z, xv.w};
#pragma unroll
            for (int j = 0; j < 4; ++j) {
                float vv = 0.5f * v[i][j] + xa[j];
                int sp = (vv >= 1.0f) ? 1 : 0;
                v[i][j] = sp ? 0.f : vv;
                Ls[nl + j][cl + 16 * i] = sp ? (f16)1.0f : (f16)0.0f;
            }
        }
        __syncthreads();
        {
            int r = tid >> 2, ch = (tid & 3) * 16;
            uint4 w0 = *(const uint4*)&Ls[r][ch];
            uint4 w1 = *(const uint4*)&Ls[r][ch + 8];
            f16* dst = s + (((size_t)t * B_ + b) * N_ + n0 + r) * (size_t)C_ + c0 + ch;
            *(uint4*)dst = w0;
            *(uint4*)(dst + 8) = w1;
        }
        __syncthreads();
    }
}

// ---------------------------------------------------------------------------
// Kernel 2: weights-stationary q/k GEMM + BN + in-register LIF.
// 4 waves = (wd: d-tile 32) x (wk: K-half 192). B-frags live in VGPRs for the
// whole kernel (96 VGPR/wave, both planes). Only A (spikes) flows through
// LDS: chunk = 32 rows = (4t x 8n) for one b, double-buffered. K-half
// partials combined via 8 KB LDS P. MFMA reg r -> t=r>>2, so the LIF
// t-recurrence runs fully in registers in the epilogue.
// Grid (128, 12): x -> (b, n-quarter), y -> 64 d' of 768 (q||k stacked).
// ---------------------------------------------------------------------------
__global__ __launch_bounds__(256, 2)
void qk_ws_kernel(const f16* __restrict__ Wq, const f16* __restrict__ Wk,
                  const f16* __restrict__ S,
                  const float* __restrict__ qg, const float* __restrict__ qb,
                  const float* __restrict__ qm, const float* __restrict__ qv,
                  const float* __restrict__ kg, const float* __restrict__ kb,
                  const float* __restrict__ km, const float* __restrict__ kv,
                  f16* __restrict__ q_spk, f16* __restrict__ k_spk)
{
    __shared__ f16 As[2][32 * 392];     // 2 x 24.5 KB, pitch 392 f16
    __shared__ float P[2][2][16][32];   // [wd][lhi][reg][l31] = 8 KB

    const int tid  = threadIdx.x;
    const int lane = tid & 63;
    const int wave = tid >> 6;
    const int wd = wave & 1;
    const int wk = wave >> 1;
    const int l31 = lane & 31;
    const int lhi = lane >> 5;

    const int mb = blockIdx.x;                       // 0..127
    const int b  = mb >> 2;
    const int n0 = (mb & 3) * 64;
    const int dp = blockIdx.y * 64 + wd * 32 + l31;  // d' in [0,768)
    const int path = (dp >= C_) ? 1 : 0;             // wave-uniform (32 | 384)
    const int dcol = dp - path * C_;

    const f16* W = path ? Wk : Wq;
    const float* g_  = path ? kg : qg;
    const float* be_ = path ? kb : qb;
    const float* m_  = path ? km : qm;
    const float* va_ = path ? kv : qv;
    f16* spk = path ? k_spk : q_spk;

    const float inv = g_[dcol] / sqrtf(va_[dcol] + EPS_);
    const float add = be_[dcol] - m_[dcol] * inv;

    // B fragments in registers: [plane][kk], K-half = wk*192
    f16x8 bf0[12], bf1[12];
    {
        const f16* wb = W + (size_t)dcol * C_ + wk * 192 + lhi * 8;
#pragma unroll
        for (int kk = 0; kk < 12; ++kk) {
            bf0[kk] = *(const f16x8*)(wb + kk * 16);
            bf1[kk] = *(const f16x8*)(wb + NW_ + kk * 16);
        }
    }

    // staging roles: wave st stages t-segment st; 8 rows x 48 16B-segs
    const int st   = tid >> 6;
    const int srow = (tid >> 3) & 7;
    const int sseg = tid & 7;
    const f16* grow_base = S + ((size_t)(st * B_ + b) * N_) * (size_t)C_;
    const int lrow = st * 8 + srow;

    // stage chunk 0 into buffer 0
    {
        int n = n0 + srow;
        const f16* gp = grow_base + (size_t)n * C_ + sseg * 8;
        f16* lp = &As[0][lrow * 392 + sseg * 8];
#pragma unroll
        for (int j = 0; j < 6; ++j)
            *(uint4*)(lp + 64 * j) = *(const uint4*)(gp + 64 * j);
    }
    __syncthreads();

    const int aoff = wk * 192 + lhi * 8;

    for (int ch = 0; ch < 8; ++ch) {
        // 1. prefetch next chunk's A rows into registers (global loads first)
        uint4 stg[6];
        if (ch < 7) {
            int n = n0 + (ch + 1) * 8 + srow;
            const f16* gp = grow_base + (size_t)n * C_ + sseg * 8;
#pragma unroll
            for (int j = 0; j < 6; ++j) stg[j] = *(const uint4*)(gp + 64 * j);
        }

        // 2. compute 32m x 32d x 192k, both planes
        const f16* ab = &As[ch & 1][l31 * 392 + aoff];
        f32x16 acc0, acc1;
#pragma unroll
        for (int r = 0; r < 16; ++r) { acc0[r] = 0.f; acc1[r] = 0.f; }
#pragma unroll
        for (int kk = 0; kk < 12; ++kk) {
            f16x8 a = *(const f16x8*)(ab + kk * 16);
            acc0 = __builtin_amdgcn_mfma_f32_32x32x16_f16(a, bf0[kk], acc0, 0, 0, 0);
            acc1 = __builtin_amdgcn_mfma_f32_32x32x16_f16(a, bf1[kk], acc1, 0, 0, 0);
        }

        // 3. drain staged regs into the other buffer; wk1 publishes partials
        if (ch < 7) {
            f16* lp = &As[(ch & 1) ^ 1][lrow * 392 + sseg * 8];
#pragma unroll
            for (int j = 0; j < 6; ++j) *(uint4*)(lp + 64 * j) = stg[j];
        }
        if (wk == 1) {
#pragma unroll
            for (int r = 0; r < 16; ++r)
                P[wd][lhi][r][l31] = acc0[r] + acc1[r] * PSCALE_INV;
        }
        __syncthreads();

        // 4. wk0: combine K-halves -> BN -> in-register LIF over t -> spikes
        if (wk == 0) {
            float pv[16];
#pragma unroll
            for (int r = 0; r < 16; ++r) pv[r] = P[wd][lhi][r][l31];
#pragma unroll
            for (int j = 0; j < 4; ++j) {
                float v = 0.f;
#pragma unroll
                for (int t = 0; t < T_; ++t) {
                    int r = 4 * t + j;
                    float val = acc0[r] + acc1[r] * PSCALE_INV + pv[r];
                    float bnv = val * inv + add;
                    float vv = 0.5f * v + bnv;
                    int sp = (vv >= 1.0f) ? 1 : 0;
                    v = sp ? 0.f : vv;
                    int n = n0 + ch * 8 + j + 4 * lhi;
                    spk[((size_t)(t * B_ + b) * N_ + n) * C_ + dcol] =
                        sp ? (f16)1.0f : (f16)0.0f;
                }
            }
        }
        __syncthreads();   // protects P (and buffers) for the next chunk
    }
}

// ---------------------------------------------------------------------------
// Kernel 3: fused head-sum + decayed memory + attention LIF.
// ---------------------------------------------------------------------------
__global__ __launch_bounds__(256)
void head_attn_kernel(const f16* __restrict__ q_spk,
                      const float* __restrict__ alpha_p,
                      unsigned char* __restrict__ attn)
{
    int i = blockIdx.x * 256 + threadIdx.x;   // B*H*N = 65536
    int n = i & (N_ - 1);
    int h = (i >> 8) & (HEADS_ - 1);
    int b = i >> 11;
    const float alpha = alpha_p[0];
    const int stride = B_ * HEADS_ * N_;
    float M = 0.f, v = 0.f, Sprev = 0.f;
#pragma unroll
    for (int t = 0; t < T_; ++t) {
        const uint4* p = (const uint4*)(q_spk + (((size_t)(t * B_ + b) * N_) + n) * C_ + h * DH_);
        int cnt = 0;
#pragma unroll
        for (int j = 0; j < 6; ++j) {
            uint4 w = p[j];
            cnt += __popc(w.x & 0x04000400u) + __popc(w.y & 0x04000400u)
                 + __popc(w.z & 0x04000400u) + __popc(w.w & 0x04000400u);
        }
        float Sqt = (float)cnt;
        if (t == 0) M = Sqt;
        else        M = alpha * M + (1.f - alpha) * Sprev;
        float qsum = M + Sqt;
        float vv = 0.5f * v + qsum;
        unsigned char sp = (vv >= 0.5f) ? 1 : 0;
        v = sp ? 0.f : vv;
        attn[(size_t)t * stride + i] = sp;
        Sprev = Sqt;
    }
}

// ---------------------------------------------------------------------------
// Kernel 4: proj GEMM. M = (tb, n) flat; block 128m x 64d, 4 waves, BK=64,
// 2 planes. A = (attn & k_spk) masked at staging. Epilogue bias+BN -> out.
// ---------------------------------------------------------------------------
__global__ __launch_bounds__(256)
void proj_gemm_kernel(const f16* __restrict__ Wp,
                      const f16* __restrict__ K,
                      const unsigned char* __restrict__ attn,
                      const float* __restrict__ bias,
                      const float* __restrict__ gamma, const float* __restrict__ beta,
                      const float* __restrict__ mean,  const float* __restrict__ var,
                      float* __restrict__ out)
{
    __shared__ __align__(16) char smem[36864];
    f16 (*As)[72]     = reinterpret_cast<f16(*)[72]>(smem);
    f16 (*Bs)[64][72] = reinterpret_cast<f16(*)[64][72]>(smem + 18432);

    const int tid  = threadIdx.x;
    const int lane = tid & 63;
    const int wave = tid >> 6;
    const int wm = wave & 1, wd = wave >> 1;
    const int l31 = lane & 31;
    const int lhi = lane >> 5;

    const int mb = blockIdx.x;            // 0..255
    const int tb = mb >> 1;
    const int n0 = (mb & 1) * 128;
    const int d0 = blockIdx.y * 64;

    const int dcol = d0 + wd * 32 + l31;
    const float iv = gamma[dcol] / sqrtf(var[dcol] + EPS_);
    const float ad = beta[dcol] - mean[dcol] * iv + bias[dcol] * iv;

    const int ar = tid >> 1;
    const int ah = (tid & 1) * 32;
    const int an = n0 + ar;
    const f16* arow = K + ((size_t)tb * N_ + an) * (size_t)C_;
    const unsigned char* At = attn + (size_t)tb * HEADS_ * N_;

    const int bp = tid >> 7;
    const int brr = (tid >> 1) & 63;
    const int bh = (tid & 1) * 32;
    const f16* brow = Wp + (size_t)bp * NW_ + (size_t)(d0 + brr) * C_;

    f32x16 acc[2][2];
#pragma unroll
    for (int ms = 0; ms < 2; ++ms)
#pragma unroll
        for (int p = 0; p < 2; ++p)
#pragma unroll
            for (int r = 0; r < 16; ++r) acc[ms][p][r] = 0.f;

    for (int kc = 0; kc < C_; kc += 64) {
        __syncthreads();
        {
#pragma unroll
            for (int j = 0; j < 4; ++j) {
                int c = kc + ah + 8 * j;
                int h = c / DH_;
                unsigned char am = At[(size_t)h * N_ + an];
                uint4 val = am ? *(const uint4*)(arow + c) : make_uint4(0u, 0u, 0u, 0u);
                *(uint4*)&As[ar][ah + 8 * j] = val;
            }
            const f16* gb = brow + kc + bh;
            *(uint4*)&Bs[bp][brr][bh]      = *(const uint4*)(gb);
            *(uint4*)&Bs[bp][brr][bh + 8]  = *(const uint4*)(gb + 8);
            *(uint4*)&Bs[bp][brr][bh + 16] = *(const uint4*)(gb + 16);
            *(uint4*)&Bs[bp][brr][bh + 24] = *(const uint4*)(gb + 24);
        }
        __syncthreads();
#pragma unroll
        for (int kk = 0; kk < 4; ++kk) {
            const int ko = kk * 16 + lhi * 8;
            f16x8 a0 = *(const f16x8*)&As[wm * 64 + l31][ko];
            f16x8 a1 = *(const f16x8*)&As[wm * 64 + 32 + l31][ko];
            f16x8 b0 = *(const f16x8*)&Bs[0][wd * 32 + l31][ko];
            f16x8 b1 = *(const f16x8*)&Bs[1][wd * 32 + l31][ko];
            acc[0][0] = __builtin_amdgcn_mfma_f32_32x32x16_f16(a0, b0, acc[0][0], 0, 0, 0);
            acc[1][0] = __builtin_amdgcn_mfma_f32_32x32x16_f16(a1, b0, acc[1][0], 0, 0, 0);
            acc[0][1] = __builtin_amdgcn_mfma_f32_32x32x16_f16(a0, b1, acc[0][1], 0, 0, 0);
            acc[1][1] = __builtin_amdgcn_mfma_f32_32x32x16_f16(a1, b1, acc[1][1], 0, 0, 0);
        }
    }

    float* obase = out + ((size_t)tb * C_ + dcol) * N_;
#pragma unroll
    for (int ms = 0; ms < 2; ++ms)
#pragma unroll
    for (int r = 0; r < 16; ++r) {
        int n = n0 + wm * 64 + ms * 32 + (r & 3) + 8 * (r >> 2) + 4 * lhi;
        float val = acc[ms][0][r] + acc[ms][1][r] * PSCALE_INV;
        obase[n] = val * iv + ad;
    }
}

// ---------------------------------------------------------------------------
extern "C" void kernel_launch(void* const* d_in, const int* in_sizes, int n_in,
                              void* d_out, int out_size, void* d_ws, size_t ws_size,
                              hipStream_t stream)
{
    const float* x       = (const float*)d_in[0];
    const float* q_w     = (const float*)d_in[1];
    const float* q_gamma = (const float*)d_in[2];
    const float* q_beta  = (const float*)d_in[3];
    const float* q_mean  = (const float*)d_in[4];
    const float* q_var   = (const float*)d_in[5];
    const float* k_w     = (const float*)d_in[6];
    const float* k_gamma = (const float*)d_in[7];
    const float* k_beta  = (const float*)d_in[8];
    const float* k_mean  = (const float*)d_in[9];
    const float* k_var   = (const float*)d_in[10];
    const float* proj_w  = (const float*)d_in[11];
    const float* proj_b  = (const float*)d_in[12];
    const float* p_gamma = (const float*)d_in[13];
    const float* p_beta  = (const float*)d_in[14];
    const float* p_mean  = (const float*)d_in[15];
    const float* p_var   = (const float*)d_in[16];
    const float* m_alpha = (const float*)d_in[17];

    float* out = (float*)d_out;

    const size_t SPK_BYTES = (size_t)T_ * B_ * N_ * C_ * sizeof(f16);
    const size_t W2_BYTES  = (size_t)2 * NW_ * sizeof(f16);

    unsigned char* ws = (unsigned char*)d_ws;
    size_t off = 0;
    auto carve = [&](size_t bytes) {
        off = (off + 255) & ~(size_t)255;
        void* p = ws + off;
        off += bytes;
        return p;
    };
    f16* s_f16  = (f16*)carve(SPK_BYTES);
    f16* q_spk  = (f16*)carve(SPK_BYTES);
    f16* k_spk  = (f16*)carve(SPK_BYTES);
    f16* Wq2    = (f16*)carve(W2_BYTES);
    f16* Wk2    = (f16*)carve(W2_BYTES);
    f16* Wp2    = (f16*)carve(W2_BYTES);
    unsigned char* attn = (unsigned char*)carve((size_t)T_ * B_ * HEADS_ * N_);

    // 1. input LIF + transpose (z<32) and weight split (z==32)
    dim3 pgrid1(4, 6, 33);
    prep_kernel<<<pgrid1, 256, 0, stream>>>(x, s_f16, q_w, k_w, proj_w, Wq2, Wk2, Wp2);

    // 2. weights-stationary q+k GEMM + BN + LIF  (grid 128 x 12 = 1536 blocks)
    dim3 qkgrid(128, 12);
    qk_ws_kernel<<<qkgrid, 256, 0, stream>>>(Wq2, Wk2, s_f16,
                                             q_gamma, q_beta, q_mean, q_var,
                                             k_gamma, k_beta, k_mean, k_var,
                                             q_spk, k_spk);

    // 3. fused head-sum + memory + attn LIF
    head_attn_kernel<<<(B_ * HEADS_ * N_) / 256, 256, 0, stream>>>(q_spk, m_alpha, attn);

    // 4. proj GEMM -> out  (grid 256 x 6 = 1536 blocks)
    dim3 pjgrid(256, 6);
    proj_gemm_kernel<<<pjgrid, 256, 0, stream>>>(Wp2, k_spk, attn, proj_b,
                                                 p_gamma, p_beta, p_mean, p_var, out);
}